// Round 2
// baseline (4164.568 us; speedup 1.0000x reference)
//
#include <hip/hip_runtime.h>
#include <math.h>

#define N_NODES 50000
#define N_EDGES 800000
#define FDIM 53
#define BATCH 128
#define HF 212   /* H*F */
#define F2 106   /* 2F  */
#define POOLW 424 /* 212+106+106 */

typedef __attribute__((ext_vector_type(8))) short short8;
typedef __attribute__((ext_vector_type(4))) float f32x4;

__device__ __forceinline__ float leaky02(float x){ return x >= 0.f ? x : 0.2f * x; }

// fp32 -> bf16 (RNE) bit helpers
__device__ __forceinline__ short f2bf(float x) {
  unsigned u = __float_as_uint(x);
  unsigned r = (u + 0x7fffu + ((u >> 16) & 1u)) >> 16;
  return (short)r;
}
__device__ __forceinline__ float bf2f(short b) {
  return __uint_as_float(((unsigned)(unsigned short)b) << 16);
}

// ---------------------------------------------------------------------------
// cAl[k*8 + sd*4 + h] = sum_f gat_w[k, h*53+f] * (sd? a_dst : a_src)[h,f]
// ---------------------------------------------------------------------------
__global__ void k_cal(const float* __restrict__ gat_w, const float* __restrict__ asrc,
                      const float* __restrict__ adst, float* __restrict__ cAl) {
  int t = threadIdx.x;
  if (t >= FDIM * 8) return;
  int k = t >> 3, r = t & 7, sd = r >> 2, h = r & 3;
  const float* av = sd ? adst : asrc;
  float acc = 0.f;
  for (int f = 0; f < FDIM; ++f) acc += gat_w[k * HF + h * FDIM + f] * av[h * FDIM + f];
  cAl[t] = acc;
}

// ---------------------------------------------------------------------------
// Fused per-node linear. v2: LDS x-tile transposed to [k][node], 8 node-accs
// per thread, broadcast ds_read_b128 feeds 8 FMAs.
// ---------------------------------------------------------------------------
#define K1_BLOCK 448
#define K1_CH 8
__global__ __launch_bounds__(K1_BLOCK) void k_nodelin(
    const float* __restrict__ x, const float* __restrict__ gat_w,
    const float* __restrict__ ec_w1, const float* __restrict__ ec_b1,
    const float* __restrict__ cAl,
    float* __restrict__ xh, float* __restrict__ U, float* __restrict__ V,
    float* __restrict__ alS, float* __restrict__ alD) {
  int j = threadIdx.x;
  float wcol[FDIM];
  float binit = 0.f;
  int mode, jj = 0;
  if (j < HF) {
    mode = 0; jj = j;
#pragma unroll
    for (int k = 0; k < FDIM; k++) wcol[k] = gat_w[k * HF + j];
  } else if (j < HF + F2) {
    mode = 1; jj = j - HF; binit = ec_b1[jj];
#pragma unroll
    for (int k = 0; k < FDIM; k++) wcol[k] = ec_w1[k * F2 + jj] - ec_w1[(FDIM + k) * F2 + jj];
  } else if (j < HF + 2 * F2) {
    mode = 2; jj = j - HF - F2;
#pragma unroll
    for (int k = 0; k < FDIM; k++) wcol[k] = ec_w1[(FDIM + k) * F2 + jj];
  } else if (j < HF + 2 * F2 + 8) {
    mode = 3; jj = j - (HF + 2 * F2);
#pragma unroll
    for (int k = 0; k < FDIM; k++) wcol[k] = cAl[k * 8 + jj];
  } else {
    mode = 4;
#pragma unroll
    for (int k = 0; k < FDIM; k++) wcol[k] = 0.f;
  }
  __shared__ float xs2[FDIM * K1_CH];   // [k][n]
  // 50000 % 8 == 0 -> all chunks full
  for (int m0 = blockIdx.x * K1_CH; m0 < N_NODES; m0 += gridDim.x * K1_CH) {
    __syncthreads();
    if (j < K1_CH * FDIM) {
      int n = j / FDIM, k = j % FDIM;           // coalesced global read
      xs2[k * K1_CH + n] = x[(size_t)m0 * FDIM + j];
    }
    __syncthreads();
    float acc[K1_CH];
#pragma unroll
    for (int n = 0; n < K1_CH; n++) acc[n] = binit;
#pragma unroll
    for (int k = 0; k < FDIM; k++) {
      const float4* p = reinterpret_cast<const float4*>(&xs2[k * K1_CH]);
      float4 a = p[0], b = p[1];
      float wk = wcol[k];
      acc[0] += wk * a.x; acc[1] += wk * a.y; acc[2] += wk * a.z; acc[3] += wk * a.w;
      acc[4] += wk * b.x; acc[5] += wk * b.y; acc[6] += wk * b.z; acc[7] += wk * b.w;
    }
#pragma unroll
    for (int n = 0; n < K1_CH; n++) {
      int i = m0 + n;
      if (mode == 0) xh[(size_t)i * HF + jj] = acc[n];
      else if (mode == 1) U[(size_t)i * F2 + jj] = acc[n];
      else if (mode == 2) V[(size_t)i * F2 + jj] = acc[n];
      else if (mode == 3) {
        if (jj < 4) alS[i * 4 + jj] = acc[n]; else alD[i * 4 + (jj - 4)] = acc[n];
      }
    }
  }
}

// ---------------------------------------------------------------------------
// CSR build: histogram, 3-phase multi-block scan, scatter
// ---------------------------------------------------------------------------
#define SCAN_BLOCKS ((N_NODES + 255) / 256)

__global__ void k_hist(const int* __restrict__ ei, const int* __restrict__ batch,
                       int* __restrict__ rp, int* __restrict__ cnt) {
  int t = blockIdx.x * blockDim.x + threadIdx.x;
  if (t < N_EDGES) atomicAdd(&rp[ei[N_EDGES + t]], 1);
  if (t < N_NODES) atomicAdd(&cnt[batch[t]], 1);
}

__global__ __launch_bounds__(256) void k_scan1(int* __restrict__ rp, int* __restrict__ bsum) {
  __shared__ int buf[256];
  int tid = threadIdx.x;
  int idx = blockIdx.x * 256 + tid;
  int v = (idx < N_NODES) ? rp[idx] : 0;
  buf[tid] = v;
  __syncthreads();
  for (int off = 1; off < 256; off <<= 1) {
    int t2 = (tid >= off) ? buf[tid - off] : 0;
    __syncthreads();
    buf[tid] += t2;
    __syncthreads();
  }
  if (idx < N_NODES) rp[idx] = buf[tid] - v;  // local exclusive
  if (tid == 255) bsum[blockIdx.x] = buf[255];
}

__global__ __launch_bounds__(256) void k_scan2(int* __restrict__ bsum) {
  __shared__ int buf[256];
  int tid = threadIdx.x;
  int v = (tid < SCAN_BLOCKS) ? bsum[tid] : 0;
  buf[tid] = v;
  __syncthreads();
  for (int off = 1; off < 256; off <<= 1) {
    int t2 = (tid >= off) ? buf[tid - off] : 0;
    __syncthreads();
    buf[tid] += t2;
    __syncthreads();
  }
  if (tid < SCAN_BLOCKS) bsum[tid] = buf[tid] - v;  // exclusive
}

__global__ __launch_bounds__(256) void k_scan3(const int* __restrict__ bsum,
                                               int* __restrict__ rp, int* __restrict__ cursor) {
  int idx = blockIdx.x * 256 + threadIdx.x;
  if (idx < N_NODES) {
    int o = rp[idx] + bsum[blockIdx.x];
    rp[idx] = o;
    cursor[idx] = o;
  }
  if (idx == 0) rp[N_NODES] = N_EDGES;
}

__global__ void k_scatter(const int* __restrict__ ei, int* __restrict__ cursor,
                          int* __restrict__ colidx) {
  int e = blockIdx.x * blockDim.x + threadIdx.x;
  if (e >= N_EDGES) return;
  int d = ei[N_EDGES + e];
  int pos = atomicAdd(&cursor[d], 1);
  colidx[pos] = ei[e];
}

// ---------------------------------------------------------------------------
// GAT: wave per node (unchanged this round)
// ---------------------------------------------------------------------------
__global__ __launch_bounds__(256) void k_gat(
    const float* __restrict__ xh, const float* __restrict__ alS, const float* __restrict__ alD,
    const float* __restrict__ bias, const int* __restrict__ rp, const int* __restrict__ colidx,
    const int* __restrict__ batch, float* __restrict__ pooled) {
  int wid = threadIdx.x >> 6, lane = threadIdx.x & 63;
  int i = blockIdx.x * 4 + wid;
  if (i >= N_NODES) return;
  int base = rp[i], deg = rp[i + 1] - base;
  float aldi[4], esf[4];
#pragma unroll
  for (int h = 0; h < 4; h++) {
    aldi[h] = alD[i * 4 + h];
    esf[h] = leaky02(alS[i * 4 + h] + aldi[h]);
  }
  float mx[4] = {-1e30f, -1e30f, -1e30f, -1e30f};
  for (int c = lane; c < deg; c += 64) {
    int s = colidx[base + c];
#pragma unroll
    for (int h = 0; h < 4; h++) mx[h] = fmaxf(mx[h], leaky02(alS[s * 4 + h] + aldi[h]));
  }
#pragma unroll
  for (int off = 32; off >= 1; off >>= 1)
#pragma unroll
    for (int h = 0; h < 4; h++) mx[h] = fmaxf(mx[h], __shfl_xor(mx[h], off));
  float m[4], exs[4];
#pragma unroll
  for (int h = 0; h < 4; h++) { m[h] = fmaxf(mx[h], esf[h]); exs[h] = __expf(esf[h] - m[h]); }

  int f0 = lane, f1 = lane + 64, f2 = lane + 128, f3 = lane + 192;
  bool v3 = (f3 < HF);
  bool h0a = f0 < FDIM;
  bool h1a = f1 < 2 * FDIM;
  bool h2a = f2 < 3 * FDIM;
  const float* xhi = xh + (size_t)i * HF;
  float acc0 = (h0a ? exs[0] : exs[1]) * xhi[f0];
  float acc1 = (h1a ? exs[1] : exs[2]) * xhi[f1];
  float acc2 = (h2a ? exs[2] : exs[3]) * xhi[f2];
  float acc3 = v3 ? exs[3] * xhi[f3] : 0.f;
  float zl[4] = {0.f, 0.f, 0.f, 0.f};

  for (int c0 = 0; c0 < deg; c0 += 64) {
    int cn = min(64, deg - c0);
    int s = 0;
    float ex0 = 0.f, ex1 = 0.f, ex2 = 0.f, ex3 = 0.f;
    if (lane < cn) {
      s = colidx[base + c0 + lane];
      ex0 = __expf(leaky02(alS[s * 4 + 0] + aldi[0]) - m[0]);
      ex1 = __expf(leaky02(alS[s * 4 + 1] + aldi[1]) - m[1]);
      ex2 = __expf(leaky02(alS[s * 4 + 2] + aldi[2]) - m[2]);
      ex3 = __expf(leaky02(alS[s * 4 + 3] + aldi[3]) - m[3]);
      zl[0] += ex0; zl[1] += ex1; zl[2] += ex2; zl[3] += ex3;
    }
    for (int jj = 0; jj < cn; jj++) {
      int sj = __shfl(s, jj);
      float a0 = __shfl(ex0, jj), a1 = __shfl(ex1, jj);
      float a2 = __shfl(ex2, jj), a3 = __shfl(ex3, jj);
      const float* xr = xh + (size_t)sj * HF;
      acc0 += (h0a ? a0 : a1) * xr[f0];
      acc1 += (h1a ? a1 : a2) * xr[f1];
      acc2 += (h2a ? a2 : a3) * xr[f2];
      if (v3) acc3 += a3 * xr[f3];
    }
  }
#pragma unroll
  for (int off = 32; off >= 1; off >>= 1)
#pragma unroll
    for (int h = 0; h < 4; h++) zl[h] += __shfl_xor(zl[h], off);
  float z[4];
#pragma unroll
  for (int h = 0; h < 4; h++) z[h] = zl[h] + exs[h] + 1e-16f;

  int b = batch[i];
  float* pg = pooled + (size_t)b * POOLW;
  float o0 = fmaxf(acc0 / (h0a ? z[0] : z[1]) + bias[f0], 0.f);
  float o1 = fmaxf(acc1 / (h1a ? z[1] : z[2]) + bias[f1], 0.f);
  float o2 = fmaxf(acc2 / (h2a ? z[2] : z[3]) + bias[f2], 0.f);
  atomicAdd(&pg[f0], o0);
  atomicAdd(&pg[f1], o1);
  atomicAdd(&pg[f2], o2);
  if (v3) {
    float o3 = fmaxf(acc3 / z[3] + bias[f3], 0.f);
    atomicAdd(&pg[f3], o3);
  }
}

// ---------------------------------------------------------------------------
// GIN: wave per node (unchanged this round)
// ---------------------------------------------------------------------------
__global__ __launch_bounds__(256) void k_gin(
    const float* __restrict__ x, const float* __restrict__ w1, const float* __restrict__ b1,
    const float* __restrict__ w2, const float* __restrict__ b2,
    const int* __restrict__ rp, const int* __restrict__ colidx, const int* __restrict__ batch,
    float* __restrict__ pooled) {
  int wid = threadIdx.x >> 6, lane = threadIdx.x & 63;
  int i = blockIdx.x * 4 + wid;
  if (i >= N_NODES) return;
  int base = rp[i], deg = rp[i + 1] - base;
  float hk = (lane < FDIM) ? x[(size_t)i * FDIM + lane] : 0.f;
  for (int c = 0; c < deg; c++) {
    int s = colidx[base + c];
    if (lane < FDIM) hk += x[(size_t)s * FDIM + lane];
  }
  int u = lane, u2 = lane + 64;
  int u2m = (u2 < F2) ? u2 : 0;
  float a1 = b1[u], a2 = b1[u2m];
#pragma unroll
  for (int k = 0; k < FDIM; k++) {
    float hb = __shfl(hk, k);
    a1 += hb * w1[k * F2 + u];
    a2 += hb * w1[k * F2 + u2m];
  }
  float h1a = fmaxf(a1, 0.f);
  float h1b = (u2 < F2) ? fmaxf(a2, 0.f) : 0.f;
  a1 = b2[u]; a2 = b2[u2m];
#pragma unroll
  for (int k = 0; k < F2; k++) {
    float hb = (k < 64) ? __shfl(h1a, k) : __shfl(h1b, k - 64);
    a1 += hb * w2[k * F2 + u];
    a2 += hb * w2[k * F2 + u2m];
  }
  int b = batch[i];
  float* pg = pooled + (size_t)b * POOLW + HF;
  atomicAdd(&pg[u], fmaxf(a1, 0.f));
  if (u2 < F2) atomicAdd(&pg[u2], fmaxf(a2, 0.f));
}

// ---------------------------------------------------------------------------
// EdgeConv v2: MFMA split-bf16. Block(256)=4 waves per node (grid-stride).
// Per 16-edge tile: stage h1=relu(U[i]+V[s]) as bf16 hi/lo in LDS (row pad
// 136 bf16 -> conflict-free b128 frag reads), D = Ah*Bh + Al*Bh + Ah*Bl via
// mfma_f32_16x16x32_bf16, K padded to 128 (4 chunks), 8 u-tiles (128 u,
// writes masked to 106). Segment max in-register via shfl_xor(16/32).
// ---------------------------------------------------------------------------
#define ROWP 136
#define KP 128
__global__ __launch_bounds__(256) void k_ec(
    const float* __restrict__ U, const float* __restrict__ V,
    const float* __restrict__ w2, const float* __restrict__ b2,
    const int* __restrict__ rp, const int* __restrict__ colidx,
    const int* __restrict__ batch, float* __restrict__ pooled) {
  const int t = threadIdx.x;
  const int lane = t & 63, wid = t >> 6;
  const int n16 = lane & 15, quad = lane >> 4;
  const int nt = (wid == 3) ? 1 : 2;   // u-tile 7 is all-pad; wave 3 does 1 tile

  // --- B fragments (w2 split into bf16 hi/lo), once per block ---
  short8 Bhi[2][4], Blo[2][4];
  for (int tt = 0; tt < 2; tt++) {
    int ucol = (wid * 2 + tt) * 16 + n16;
    for (int kc = 0; kc < 4; kc++) {
      short8 vh, vl;
#pragma unroll
      for (int jv = 0; jv < 8; jv++) {
        int kk = kc * 32 + quad * 8 + jv;
        float w = (ucol < F2 && kk < F2) ? w2[kk * F2 + ucol] : 0.f;
        short h = f2bf(w);
        vh[jv] = h;
        vl[jv] = f2bf(w - bf2f(h));
      }
      Bhi[tt][kc] = vh; Blo[tt][kc] = vl;
    }
  }
  float b2v[2];
#pragma unroll
  for (int tt = 0; tt < 2; tt++) {
    int u = (wid * 2 + tt) * 16 + n16;
    b2v[tt] = (u < F2) ? b2[u] : 0.f;
  }

  __shared__ float Us[KP];
  __shared__ short h1hi[16 * ROWP];
  __shared__ short h1lo[16 * ROWP];

  const int es = t >> 4, kg = t & 15;  // staging role: edge, k-group
  for (int i = blockIdx.x; i < N_NODES; i += gridDim.x) {
    int base = rp[i], deg = rp[i + 1] - base;
    if (deg == 0) continue;
    if (t < KP) Us[t] = (t < F2) ? U[(size_t)i * F2 + t] : 0.f;
    float vmax0 = -1e30f, vmax1 = -1e30f;
    int ntile = (deg + 15) >> 4;
    for (int tb = 0; tb < ntile; tb++) {
      int eg = tb * 16 + es;
      bool realE = eg < deg;
      int s = realE ? colidx[base + eg] : 0;
      const float* Vr = V + (size_t)s * F2;
      int k0 = kg * 8;
      __syncthreads();   // prev tile's frag reads done (also publishes Us on tb==0)
      short8 wh, wl;
#pragma unroll
      for (int jv = 0; jv < 8; jv++) {
        int kk = k0 + jv;
        float h = 0.f;
        if (realE && kk < F2) h = fmaxf(Us[kk] + Vr[kk], 0.f);
        short hb = f2bf(h);
        wh[jv] = hb;
        wl[jv] = f2bf(h - bf2f(hb));
      }
      *(short8*)&h1hi[es * ROWP + k0] = wh;
      *(short8*)&h1lo[es * ROWP + k0] = wl;
      __syncthreads();
      f32x4 a0 = {0.f, 0.f, 0.f, 0.f}, a1 = {0.f, 0.f, 0.f, 0.f};
#pragma unroll
      for (int kc = 0; kc < 4; kc++) {
        short8 ah = *(const short8*)&h1hi[n16 * ROWP + kc * 32 + quad * 8];
        short8 al = *(const short8*)&h1lo[n16 * ROWP + kc * 32 + quad * 8];
        a0 = __builtin_amdgcn_mfma_f32_16x16x32_bf16(ah, Bhi[0][kc], a0, 0, 0, 0);
        a0 = __builtin_amdgcn_mfma_f32_16x16x32_bf16(al, Bhi[0][kc], a0, 0, 0, 0);
        a0 = __builtin_amdgcn_mfma_f32_16x16x32_bf16(ah, Blo[0][kc], a0, 0, 0, 0);
        if (nt > 1) {
          a1 = __builtin_amdgcn_mfma_f32_16x16x32_bf16(ah, Bhi[1][kc], a1, 0, 0, 0);
          a1 = __builtin_amdgcn_mfma_f32_16x16x32_bf16(al, Bhi[1][kc], a1, 0, 0, 0);
          a1 = __builtin_amdgcn_mfma_f32_16x16x32_bf16(ah, Blo[1][kc], a1, 0, 0, 0);
        }
      }
      float m0 = -1e30f, m1 = -1e30f;
#pragma unroll
      for (int r = 0; r < 4; r++) {
        int er = tb * 16 + quad * 4 + r;
        if (er < deg) { m0 = fmaxf(m0, a0[r]); m1 = fmaxf(m1, a1[r]); }
      }
      m0 = fmaxf(m0, __shfl_xor(m0, 16)); m0 = fmaxf(m0, __shfl_xor(m0, 32));
      m1 = fmaxf(m1, __shfl_xor(m1, 16)); m1 = fmaxf(m1, __shfl_xor(m1, 32));
      vmax0 = fmaxf(vmax0, m0);
      vmax1 = fmaxf(vmax1, m1);
    }
    // pool: relu(max + b2) from quad 0 lanes
    if (quad == 0) {
      int b = batch[i];
      float* pg = pooled + (size_t)b * POOLW + HF + F2;
      int u0 = (wid * 2) * 16 + n16;
      if (u0 < F2) atomicAdd(&pg[u0], fmaxf(vmax0 + b2v[0], 0.f));
      int u1 = (wid * 2 + 1) * 16 + n16;
      if (nt > 1 && u1 < F2) atomicAdd(&pg[u1], fmaxf(vmax1 + b2v[1], 0.f));
    }
  }
}

// ---------------------------------------------------------------------------
// mean-pool divide, generic small dense
// ---------------------------------------------------------------------------
__global__ void k_pooldiv(float* __restrict__ pooled, const int* __restrict__ cnt) {
  int t = blockIdx.x * blockDim.x + threadIdx.x;
  if (t >= BATCH * POOLW) return;
  int b = t / POOLW;
  pooled[t] /= fmaxf((float)cnt[b], 1.f);
}

__global__ void k_dense(const float* __restrict__ A, int lda, const float* __restrict__ W,
                        const float* __restrict__ bias, float* __restrict__ C, int ldc,
                        int M, int K, int N, int act) {
  int t = blockIdx.x * blockDim.x + threadIdx.x;
  if (t >= M * N) return;
  int mm = t / N, nn = t % N;
  float acc = bias[nn];
  for (int k = 0; k < K; k++) acc += A[(size_t)mm * lda + k] * W[(size_t)k * N + nn];
  if (act == 1) acc = fmaxf(acc, 0.f);
  else if (act == 2) acc = 1.f / (1.f + __expf(-acc));
  C[(size_t)mm * ldc + nn] = acc;
}

// ---------------------------------------------------------------------------
extern "C" void kernel_launch(void* const* d_in, const int* in_sizes, int n_in,
                              void* d_out, int out_size, void* d_ws, size_t ws_size,
                              hipStream_t stream) {
  const float* x      = (const float*)d_in[0];
  const int*   ei     = (const int*)d_in[1];
  const int*   batch  = (const int*)d_in[2];
  const float* gat_w  = (const float*)d_in[3];
  const float* asrc   = (const float*)d_in[4];
  const float* adst   = (const float*)d_in[5];
  const float* gat_b  = (const float*)d_in[6];
  const float* gin_w1 = (const float*)d_in[7];
  const float* gin_b1 = (const float*)d_in[8];
  const float* gin_w2 = (const float*)d_in[9];
  const float* gin_b2 = (const float*)d_in[10];
  const float* ec_w1  = (const float*)d_in[11];
  const float* ec_b1  = (const float*)d_in[12];
  const float* ec_w2  = (const float*)d_in[13];
  const float* ec_b2  = (const float*)d_in[14];
  const float* fg1_w = (const float*)d_in[15]; const float* fg1_b = (const float*)d_in[16];
  const float* fg2_w = (const float*)d_in[17]; const float* fg2_b = (const float*)d_in[18];
  const float* fg3_w = (const float*)d_in[19]; const float* fg3_b = (const float*)d_in[20];
  const float* fg4_w = (const float*)d_in[21]; const float* fg4_b = (const float*)d_in[22];
  const float* fg5_w = (const float*)d_in[23]; const float* fg5_b = (const float*)d_in[24];
  const float* fg6_w = (const float*)d_in[25]; const float* fg6_b = (const float*)d_in[26];
  const float* fc1_w = (const float*)d_in[27]; const float* fc1_b = (const float*)d_in[28];
  const float* fc2_w = (const float*)d_in[29]; const float* fc2_b = (const float*)d_in[30];
  const float* out_w = (const float*)d_in[31]; const float* out_b = (const float*)d_in[32];
  float* out = (float*)d_out;

  char* ws = (char*)d_ws;
  size_t off = 0;
  auto alloc = [&](size_t bytes) -> void* {
    void* p = ws + off;
    off = (off + bytes + 255) & ~(size_t)255;
    return p;
  };
  // --- zero region (one memset): rp | cnt | pooled ---
  size_t zoff0 = off;
  int*   rp     = (int*)alloc((N_NODES + 1) * sizeof(int));
  int*   cnt    = (int*)alloc(BATCH * sizeof(int));
  float* pooled = (float*)alloc((size_t)BATCH * POOLW * sizeof(float));
  size_t zbytes = off - zoff0;
  // --- rest ---
  int*   cursor = (int*)alloc(N_NODES * sizeof(int));
  int*   bsum   = (int*)alloc(256 * sizeof(int));
  int*   colidx = (int*)alloc(N_EDGES * sizeof(int));
  float* xh     = (float*)alloc((size_t)N_NODES * HF * sizeof(float));
  float* alS    = (float*)alloc((size_t)N_NODES * 4 * sizeof(float));
  float* alD    = (float*)alloc((size_t)N_NODES * 4 * sizeof(float));
  float* Ubuf   = (float*)alloc((size_t)N_NODES * F2 * sizeof(float));
  float* Vbuf   = (float*)alloc((size_t)N_NODES * F2 * sizeof(float));
  float* cAl    = (float*)alloc(FDIM * 8 * sizeof(float));
  float* t1     = (float*)alloc((size_t)BATCH * 256 * sizeof(float));
  float* cat    = (float*)alloc((size_t)BATCH * 384 * sizeof(float));
  float* t3     = (float*)alloc((size_t)BATCH * 128 * sizeof(float));
  float* t4     = (float*)alloc((size_t)BATCH * 64 * sizeof(float));
  (void)ws_size; (void)in_sizes; (void)n_in; (void)out_size;

  hipMemsetAsync(ws + zoff0, 0, zbytes, stream);

  k_cal<<<1, 448, 0, stream>>>(gat_w, asrc, adst, cAl);
  k_nodelin<<<512, K1_BLOCK, 0, stream>>>(x, gat_w, ec_w1, ec_b1, cAl,
                                          xh, Ubuf, Vbuf, alS, alD);
  k_hist<<<(N_EDGES + 255) / 256, 256, 0, stream>>>(ei, batch, rp, cnt);
  k_scan1<<<SCAN_BLOCKS, 256, 0, stream>>>(rp, bsum);
  k_scan2<<<1, 256, 0, stream>>>(bsum);
  k_scan3<<<SCAN_BLOCKS, 256, 0, stream>>>(bsum, rp, cursor);
  k_scatter<<<(N_EDGES + 255) / 256, 256, 0, stream>>>(ei, cursor, colidx);

  k_gat<<<(N_NODES + 3) / 4, 256, 0, stream>>>(xh, alS, alD, gat_b, rp, colidx, batch, pooled);
  k_gin<<<(N_NODES + 3) / 4, 256, 0, stream>>>(x, gin_w1, gin_b1, gin_w2, gin_b2,
                                               rp, colidx, batch, pooled);
  k_ec<<<2048, 256, 0, stream>>>(Ubuf, Vbuf, ec_w2, ec_b2, rp, colidx, batch, pooled);

  k_pooldiv<<<(BATCH * POOLW + 255) / 256, 256, 0, stream>>>(pooled, cnt);

  // heads: gat | gin | ec -> cat[128,384]
  k_dense<<<(128 * 256 + 255) / 256, 256, 0, stream>>>(pooled + 0, POOLW, fg1_w, fg1_b, t1, 256, 128, HF, 256, 1);
  k_dense<<<(128 * 128 + 255) / 256, 256, 0, stream>>>(t1, 256, fg2_w, fg2_b, cat + 0, 384, 128, 256, 128, 1);
  k_dense<<<(128 * 256 + 255) / 256, 256, 0, stream>>>(pooled + HF, POOLW, fg3_w, fg3_b, t1, 256, 128, F2, 256, 1);
  k_dense<<<(128 * 128 + 255) / 256, 256, 0, stream>>>(t1, 256, fg4_w, fg4_b, cat + 128, 384, 128, 256, 128, 1);
  k_dense<<<(128 * 256 + 255) / 256, 256, 0, stream>>>(pooled + HF + F2, POOLW, fg5_w, fg5_b, t1, 256, 128, F2, 256, 1);
  k_dense<<<(128 * 128 + 255) / 256, 256, 0, stream>>>(t1, 256, fg6_w, fg6_b, cat + 256, 384, 128, 256, 128, 1);
  // final MLP
  k_dense<<<(128 * 128 + 255) / 256, 256, 0, stream>>>(cat, 384, fc1_w, fc1_b, t3, 128, 128, 384, 128, 1);
  k_dense<<<(128 * 64 + 255) / 256, 256, 0, stream>>>(t3, 128, fc2_w, fc2_b, t4, 64, 128, 128, 64, 1);
  k_dense<<<1, 128, 0, stream>>>(t4, 64, out_w, out_b, out, 1, 128, 64, 1, 2);
}

// Round 3
// 1630.049 us; speedup vs baseline: 2.5549x; 2.5549x over previous
//
#include <hip/hip_runtime.h>
#include <math.h>

#define N_NODES 50000
#define N_EDGES 800000
#define FDIM 53
#define BATCH 128
#define HF 212   /* H*F */
#define F2 106   /* 2F  */
#define POOLW 424 /* 212+106+106 */
#define NPACK 432 /* 212 + 106 + 106 + 8 */

typedef __attribute__((ext_vector_type(8))) short short8;
typedef __attribute__((ext_vector_type(4))) float f32x4;

__device__ __forceinline__ float leaky02(float x){ return x >= 0.f ? x : 0.2f * x; }

// fp32 -> bf16 (RNE) bit helpers
__device__ __forceinline__ short f2bf(float x) {
  unsigned u = __float_as_uint(x);
  unsigned r = (u + 0x7fffu + ((u >> 16) & 1u)) >> 16;
  return (short)r;
}
__device__ __forceinline__ float bf2f(short b) {
  return __uint_as_float(((unsigned)(unsigned short)b) << 16);
}

// ---------------------------------------------------------------------------
// cAl[k*8 + sd*4 + h] = sum_f gat_w[k, h*53+f] * (sd? a_dst : a_src)[h,f]
// ---------------------------------------------------------------------------
__global__ void k_cal(const float* __restrict__ gat_w, const float* __restrict__ asrc,
                      const float* __restrict__ adst, float* __restrict__ cAl) {
  int t = threadIdx.x;
  if (t >= FDIM * 8) return;
  int k = t >> 3, r = t & 7, sd = r >> 2, h = r & 3;
  const float* av = sd ? adst : asrc;
  float acc = 0.f;
  for (int f = 0; f < FDIM; ++f) acc += gat_w[k * HF + h * FDIM + f] * av[h * FDIM + f];
  cAl[t] = acc;
}

// ---------------------------------------------------------------------------
// Pack Wp[53][432] = [gat_w | W1top-W1bot | W1bot | cAl] and bias bp[432]
// ---------------------------------------------------------------------------
__global__ void k_prep(const float* __restrict__ gat_w, const float* __restrict__ ec_w1,
                       const float* __restrict__ ec_b1, const float* __restrict__ cAl,
                       float* __restrict__ Wp, float* __restrict__ bp) {
  int idx = blockIdx.x * blockDim.x + threadIdx.x;
  if (idx < FDIM * NPACK) {
    int k = idx / NPACK, j = idx % NPACK;
    float v;
    if (j < HF)            v = gat_w[k * HF + j];
    else if (j < HF + F2)  v = ec_w1[k * F2 + (j - HF)] - ec_w1[(FDIM + k) * F2 + (j - HF)];
    else if (j < POOLW)    v = ec_w1[(FDIM + k) * F2 + (j - HF - F2)];
    else                   v = cAl[k * 8 + (j - POOLW)];
    Wp[idx] = v;
  }
  if (idx < NPACK) {
    bp[idx] = (idx >= HF && idx < HF + F2) ? ec_b1[idx - HF] : 0.f;
  }
}

// ---------------------------------------------------------------------------
// Node-linear as tiled fp32 GEMM: x[50000x53] @ Wp[53x432] + bp.
// Tile 64(M) x 144(N), 256 threads, 4x9 acc/thread. Outputs scattered to
// xh / U / V / alS / alD. ~60 VGPR, no spills.
// ---------------------------------------------------------------------------
#define GM 64
#define GN 144
#define APAD 57
__global__ __launch_bounds__(256) void k_gemm(
    const float* __restrict__ x, const float* __restrict__ Wp, const float* __restrict__ bp,
    float* __restrict__ xh, float* __restrict__ U, float* __restrict__ V,
    float* __restrict__ alS, float* __restrict__ alD) {
  __shared__ float As[GM * APAD];     // [m][k] pad 57: 14.6 KB
  __shared__ float Ws[FDIM * GN];     // [k][n]: 30.5 KB
  int mb = blockIdx.x / 3, nc = blockIdx.x % 3;
  int m0 = mb * GM, n0 = nc * GN;
  int t = threadIdx.x;
  for (int idx = t; idx < GM * FDIM; idx += 256) {
    int m = idx / FDIM, k = idx % FDIM;        // coalesced global read of x
    int gm = m0 + m;
    As[m * APAD + k] = (gm < N_NODES) ? x[(size_t)gm * FDIM + k] : 0.f;
  }
  for (int idx = t; idx < FDIM * GN; idx += 256) {
    int k = idx / GN, n = idx % GN;
    Ws[idx] = Wp[k * NPACK + n0 + n];
  }
  __syncthreads();
  int tx = t & 15, ty = t >> 4;
  int ms = tx * 4, ns = ty * 9;
  float acc[4][9];
#pragma unroll
  for (int i = 0; i < 4; i++)
#pragma unroll
    for (int j = 0; j < 9; j++) acc[i][j] = 0.f;
  for (int k = 0; k < FDIM; k++) {
    float a0 = As[(ms + 0) * APAD + k];
    float a1 = As[(ms + 1) * APAD + k];
    float a2 = As[(ms + 2) * APAD + k];
    float a3 = As[(ms + 3) * APAD + k];
    float b[9];
#pragma unroll
    for (int j = 0; j < 9; j++) b[j] = Ws[k * GN + ns + j];
#pragma unroll
    for (int j = 0; j < 9; j++) {
      acc[0][j] += a0 * b[j];
      acc[1][j] += a1 * b[j];
      acc[2][j] += a2 * b[j];
      acc[3][j] += a3 * b[j];
    }
  }
  float bj[9];
#pragma unroll
  for (int j = 0; j < 9; j++) bj[j] = bp[n0 + ns + j];
#pragma unroll
  for (int i = 0; i < 4; i++) {
    int gm = m0 + ms + i;
    if (gm >= N_NODES) break;
#pragma unroll
    for (int j = 0; j < 9; j++) {
      int g = n0 + ns + j;
      float v = acc[i][j] + bj[j];
      if (g < HF)            xh[(size_t)gm * HF + g] = v;
      else if (g < HF + F2)  U[(size_t)gm * F2 + (g - HF)] = v;
      else if (g < POOLW)    V[(size_t)gm * F2 + (g - HF - F2)] = v;
      else if (g < POOLW + 4) alS[gm * 4 + (g - POOLW)] = v;
      else                   alD[gm * 4 + (g - POOLW - 4)] = v;
    }
  }
}

// ---------------------------------------------------------------------------
// CSR build: histogram, 3-phase multi-block scan, scatter
// ---------------------------------------------------------------------------
#define SCAN_BLOCKS ((N_NODES + 255) / 256)

__global__ void k_hist(const int* __restrict__ ei, const int* __restrict__ batch,
                       int* __restrict__ rp, int* __restrict__ cnt) {
  int t = blockIdx.x * blockDim.x + threadIdx.x;
  if (t < N_EDGES) atomicAdd(&rp[ei[N_EDGES + t]], 1);
  if (t < N_NODES) atomicAdd(&cnt[batch[t]], 1);
}

__global__ __launch_bounds__(256) void k_scan1(int* __restrict__ rp, int* __restrict__ bsum) {
  __shared__ int buf[256];
  int tid = threadIdx.x;
  int idx = blockIdx.x * 256 + tid;
  int v = (idx < N_NODES) ? rp[idx] : 0;
  buf[tid] = v;
  __syncthreads();
  for (int off = 1; off < 256; off <<= 1) {
    int t2 = (tid >= off) ? buf[tid - off] : 0;
    __syncthreads();
    buf[tid] += t2;
    __syncthreads();
  }
  if (idx < N_NODES) rp[idx] = buf[tid] - v;  // local exclusive
  if (tid == 255) bsum[blockIdx.x] = buf[255];
}

__global__ __launch_bounds__(256) void k_scan2(int* __restrict__ bsum) {
  __shared__ int buf[256];
  int tid = threadIdx.x;
  int v = (tid < SCAN_BLOCKS) ? bsum[tid] : 0;
  buf[tid] = v;
  __syncthreads();
  for (int off = 1; off < 256; off <<= 1) {
    int t2 = (tid >= off) ? buf[tid - off] : 0;
    __syncthreads();
    buf[tid] += t2;
    __syncthreads();
  }
  if (tid < SCAN_BLOCKS) bsum[tid] = buf[tid] - v;  // exclusive
}

__global__ __launch_bounds__(256) void k_scan3(const int* __restrict__ bsum,
                                               int* __restrict__ rp, int* __restrict__ cursor) {
  int idx = blockIdx.x * 256 + threadIdx.x;
  if (idx < N_NODES) {
    int o = rp[idx] + bsum[blockIdx.x];
    rp[idx] = o;
    cursor[idx] = o;
  }
  if (idx == 0) rp[N_NODES] = N_EDGES;
}

__global__ void k_scatter(const int* __restrict__ ei, int* __restrict__ cursor,
                          int* __restrict__ colidx) {
  int e = blockIdx.x * blockDim.x + threadIdx.x;
  if (e >= N_EDGES) return;
  int d = ei[N_EDGES + e];
  int pos = atomicAdd(&cursor[d], 1);
  colidx[pos] = ei[e];
}

// ---------------------------------------------------------------------------
// GAT: wave per node
// ---------------------------------------------------------------------------
__global__ __launch_bounds__(256) void k_gat(
    const float* __restrict__ xh, const float* __restrict__ alS, const float* __restrict__ alD,
    const float* __restrict__ bias, const int* __restrict__ rp, const int* __restrict__ colidx,
    const int* __restrict__ batch, float* __restrict__ pooled) {
  int wid = threadIdx.x >> 6, lane = threadIdx.x & 63;
  int i = blockIdx.x * 4 + wid;
  if (i >= N_NODES) return;
  int base = rp[i], deg = rp[i + 1] - base;
  float aldi[4], esf[4];
#pragma unroll
  for (int h = 0; h < 4; h++) {
    aldi[h] = alD[i * 4 + h];
    esf[h] = leaky02(alS[i * 4 + h] + aldi[h]);
  }
  float mx[4] = {-1e30f, -1e30f, -1e30f, -1e30f};
  for (int c = lane; c < deg; c += 64) {
    int s = colidx[base + c];
#pragma unroll
    for (int h = 0; h < 4; h++) mx[h] = fmaxf(mx[h], leaky02(alS[s * 4 + h] + aldi[h]));
  }
#pragma unroll
  for (int off = 32; off >= 1; off >>= 1)
#pragma unroll
    for (int h = 0; h < 4; h++) mx[h] = fmaxf(mx[h], __shfl_xor(mx[h], off));
  float m[4], exs[4];
#pragma unroll
  for (int h = 0; h < 4; h++) { m[h] = fmaxf(mx[h], esf[h]); exs[h] = __expf(esf[h] - m[h]); }

  int f0 = lane, f1 = lane + 64, f2 = lane + 128, f3 = lane + 192;
  bool v3 = (f3 < HF);
  bool h0a = f0 < FDIM;
  bool h1a = f1 < 2 * FDIM;
  bool h2a = f2 < 3 * FDIM;
  const float* xhi = xh + (size_t)i * HF;
  float acc0 = (h0a ? exs[0] : exs[1]) * xhi[f0];
  float acc1 = (h1a ? exs[1] : exs[2]) * xhi[f1];
  float acc2 = (h2a ? exs[2] : exs[3]) * xhi[f2];
  float acc3 = v3 ? exs[3] * xhi[f3] : 0.f;
  float zl[4] = {0.f, 0.f, 0.f, 0.f};

  for (int c0 = 0; c0 < deg; c0 += 64) {
    int cn = min(64, deg - c0);
    int s = 0;
    float ex0 = 0.f, ex1 = 0.f, ex2 = 0.f, ex3 = 0.f;
    if (lane < cn) {
      s = colidx[base + c0 + lane];
      ex0 = __expf(leaky02(alS[s * 4 + 0] + aldi[0]) - m[0]);
      ex1 = __expf(leaky02(alS[s * 4 + 1] + aldi[1]) - m[1]);
      ex2 = __expf(leaky02(alS[s * 4 + 2] + aldi[2]) - m[2]);
      ex3 = __expf(leaky02(alS[s * 4 + 3] + aldi[3]) - m[3]);
      zl[0] += ex0; zl[1] += ex1; zl[2] += ex2; zl[3] += ex3;
    }
    for (int jj = 0; jj < cn; jj++) {
      int sj = __shfl(s, jj);
      float a0 = __shfl(ex0, jj), a1 = __shfl(ex1, jj);
      float a2 = __shfl(ex2, jj), a3 = __shfl(ex3, jj);
      const float* xr = xh + (size_t)sj * HF;
      acc0 += (h0a ? a0 : a1) * xr[f0];
      acc1 += (h1a ? a1 : a2) * xr[f1];
      acc2 += (h2a ? a2 : a3) * xr[f2];
      if (v3) acc3 += a3 * xr[f3];
    }
  }
#pragma unroll
  for (int off = 32; off >= 1; off >>= 1)
#pragma unroll
    for (int h = 0; h < 4; h++) zl[h] += __shfl_xor(zl[h], off);
  float z[4];
#pragma unroll
  for (int h = 0; h < 4; h++) z[h] = zl[h] + exs[h] + 1e-16f;

  int b = batch[i];
  float* pg = pooled + (size_t)b * POOLW;
  float o0 = fmaxf(acc0 / (h0a ? z[0] : z[1]) + bias[f0], 0.f);
  float o1 = fmaxf(acc1 / (h1a ? z[1] : z[2]) + bias[f1], 0.f);
  float o2 = fmaxf(acc2 / (h2a ? z[2] : z[3]) + bias[f2], 0.f);
  atomicAdd(&pg[f0], o0);
  atomicAdd(&pg[f1], o1);
  atomicAdd(&pg[f2], o2);
  if (v3) {
    float o3 = fmaxf(acc3 / z[3] + bias[f3], 0.f);
    atomicAdd(&pg[f3], o3);
  }
}

// ---------------------------------------------------------------------------
// GIN: wave per node
// ---------------------------------------------------------------------------
__global__ __launch_bounds__(256) void k_gin(
    const float* __restrict__ x, const float* __restrict__ w1, const float* __restrict__ b1,
    const float* __restrict__ w2, const float* __restrict__ b2,
    const int* __restrict__ rp, const int* __restrict__ colidx, const int* __restrict__ batch,
    float* __restrict__ pooled) {
  int wid = threadIdx.x >> 6, lane = threadIdx.x & 63;
  int i = blockIdx.x * 4 + wid;
  if (i >= N_NODES) return;
  int base = rp[i], deg = rp[i + 1] - base;
  float hk = (lane < FDIM) ? x[(size_t)i * FDIM + lane] : 0.f;
  for (int c = 0; c < deg; c++) {
    int s = colidx[base + c];
    if (lane < FDIM) hk += x[(size_t)s * FDIM + lane];
  }
  int u = lane, u2 = lane + 64;
  int u2m = (u2 < F2) ? u2 : 0;
  float a1 = b1[u], a2 = b1[u2m];
#pragma unroll
  for (int k = 0; k < FDIM; k++) {
    float hb = __shfl(hk, k);
    a1 += hb * w1[k * F2 + u];
    a2 += hb * w1[k * F2 + u2m];
  }
  float h1a = fmaxf(a1, 0.f);
  float h1b = (u2 < F2) ? fmaxf(a2, 0.f) : 0.f;
  a1 = b2[u]; a2 = b2[u2m];
#pragma unroll
  for (int k = 0; k < F2; k++) {
    float hb = (k < 64) ? __shfl(h1a, k) : __shfl(h1b, k - 64);
    a1 += hb * w2[k * F2 + u];
    a2 += hb * w2[k * F2 + u2m];
  }
  int b = batch[i];
  float* pg = pooled + (size_t)b * POOLW + HF;
  atomicAdd(&pg[u], fmaxf(a1, 0.f));
  if (u2 < F2) atomicAdd(&pg[u2], fmaxf(a2, 0.f));
}

// ---------------------------------------------------------------------------
// EdgeConv: MFMA split-bf16 (unchanged this round)
// ---------------------------------------------------------------------------
#define ROWP 136
#define KP 128
__global__ __launch_bounds__(256) void k_ec(
    const float* __restrict__ U, const float* __restrict__ V,
    const float* __restrict__ w2, const float* __restrict__ b2,
    const int* __restrict__ rp, const int* __restrict__ colidx,
    const int* __restrict__ batch, float* __restrict__ pooled) {
  const int t = threadIdx.x;
  const int lane = t & 63, wid = t >> 6;
  const int n16 = lane & 15, quad = lane >> 4;
  const int nt = (wid == 3) ? 1 : 2;

  short8 Bhi[2][4], Blo[2][4];
  for (int tt = 0; tt < 2; tt++) {
    int ucol = (wid * 2 + tt) * 16 + n16;
    for (int kc = 0; kc < 4; kc++) {
      short8 vh, vl;
#pragma unroll
      for (int jv = 0; jv < 8; jv++) {
        int kk = kc * 32 + quad * 8 + jv;
        float w = (ucol < F2 && kk < F2) ? w2[kk * F2 + ucol] : 0.f;
        short h = f2bf(w);
        vh[jv] = h;
        vl[jv] = f2bf(w - bf2f(h));
      }
      Bhi[tt][kc] = vh; Blo[tt][kc] = vl;
    }
  }
  float b2v[2];
#pragma unroll
  for (int tt = 0; tt < 2; tt++) {
    int u = (wid * 2 + tt) * 16 + n16;
    b2v[tt] = (u < F2) ? b2[u] : 0.f;
  }

  __shared__ float Us[KP];
  __shared__ short h1hi[16 * ROWP];
  __shared__ short h1lo[16 * ROWP];

  const int es = t >> 4, kg = t & 15;
  for (int i = blockIdx.x; i < N_NODES; i += gridDim.x) {
    int base = rp[i], deg = rp[i + 1] - base;
    if (deg == 0) continue;
    if (t < KP) Us[t] = (t < F2) ? U[(size_t)i * F2 + t] : 0.f;
    float vmax0 = -1e30f, vmax1 = -1e30f;
    int ntile = (deg + 15) >> 4;
    for (int tb = 0; tb < ntile; tb++) {
      int eg = tb * 16 + es;
      bool realE = eg < deg;
      int s = realE ? colidx[base + eg] : 0;
      const float* Vr = V + (size_t)s * F2;
      int k0 = kg * 8;
      __syncthreads();
      short8 wh, wl;
#pragma unroll
      for (int jv = 0; jv < 8; jv++) {
        int kk = k0 + jv;
        float h = 0.f;
        if (realE && kk < F2) h = fmaxf(Us[kk] + Vr[kk], 0.f);
        short hb = f2bf(h);
        wh[jv] = hb;
        wl[jv] = f2bf(h - bf2f(hb));
      }
      *(short8*)&h1hi[es * ROWP + k0] = wh;
      *(short8*)&h1lo[es * ROWP + k0] = wl;
      __syncthreads();
      f32x4 a0 = {0.f, 0.f, 0.f, 0.f}, a1 = {0.f, 0.f, 0.f, 0.f};
#pragma unroll
      for (int kc = 0; kc < 4; kc++) {
        short8 ah = *(const short8*)&h1hi[n16 * ROWP + kc * 32 + quad * 8];
        short8 al = *(const short8*)&h1lo[n16 * ROWP + kc * 32 + quad * 8];
        a0 = __builtin_amdgcn_mfma_f32_16x16x32_bf16(ah, Bhi[0][kc], a0, 0, 0, 0);
        a0 = __builtin_amdgcn_mfma_f32_16x16x32_bf16(al, Bhi[0][kc], a0, 0, 0, 0);
        a0 = __builtin_amdgcn_mfma_f32_16x16x32_bf16(ah, Blo[0][kc], a0, 0, 0, 0);
        if (nt > 1) {
          a1 = __builtin_amdgcn_mfma_f32_16x16x32_bf16(ah, Bhi[1][kc], a1, 0, 0, 0);
          a1 = __builtin_amdgcn_mfma_f32_16x16x32_bf16(al, Bhi[1][kc], a1, 0, 0, 0);
          a1 = __builtin_amdgcn_mfma_f32_16x16x32_bf16(ah, Blo[1][kc], a1, 0, 0, 0);
        }
      }
      float m0 = -1e30f, m1 = -1e30f;
#pragma unroll
      for (int r = 0; r < 4; r++) {
        int er = tb * 16 + quad * 4 + r;
        if (er < deg) { m0 = fmaxf(m0, a0[r]); m1 = fmaxf(m1, a1[r]); }
      }
      m0 = fmaxf(m0, __shfl_xor(m0, 16)); m0 = fmaxf(m0, __shfl_xor(m0, 32));
      m1 = fmaxf(m1, __shfl_xor(m1, 16)); m1 = fmaxf(m1, __shfl_xor(m1, 32));
      vmax0 = fmaxf(vmax0, m0);
      vmax1 = fmaxf(vmax1, m1);
    }
    if (quad == 0) {
      int b = batch[i];
      float* pg = pooled + (size_t)b * POOLW + HF + F2;
      int u0 = (wid * 2) * 16 + n16;
      if (u0 < F2) atomicAdd(&pg[u0], fmaxf(vmax0 + b2v[0], 0.f));
      int u1 = (wid * 2 + 1) * 16 + n16;
      if (nt > 1 && u1 < F2) atomicAdd(&pg[u1], fmaxf(vmax1 + b2v[1], 0.f));
    }
  }
}

// ---------------------------------------------------------------------------
// mean-pool divide, generic small dense
// ---------------------------------------------------------------------------
__global__ void k_pooldiv(float* __restrict__ pooled, const int* __restrict__ cnt) {
  int t = blockIdx.x * blockDim.x + threadIdx.x;
  if (t >= BATCH * POOLW) return;
  int b = t / POOLW;
  pooled[t] /= fmaxf((float)cnt[b], 1.f);
}

__global__ void k_dense(const float* __restrict__ A, int lda, const float* __restrict__ W,
                        const float* __restrict__ bias, float* __restrict__ C, int ldc,
                        int M, int K, int N, int act) {
  int t = blockIdx.x * blockDim.x + threadIdx.x;
  if (t >= M * N) return;
  int mm = t / N, nn = t % N;
  float acc = bias[nn];
  for (int k = 0; k < K; k++) acc += A[(size_t)mm * lda + k] * W[(size_t)k * N + nn];
  if (act == 1) acc = fmaxf(acc, 0.f);
  else if (act == 2) acc = 1.f / (1.f + __expf(-acc));
  C[(size_t)mm * ldc + nn] = acc;
}

// ---------------------------------------------------------------------------
extern "C" void kernel_launch(void* const* d_in, const int* in_sizes, int n_in,
                              void* d_out, int out_size, void* d_ws, size_t ws_size,
                              hipStream_t stream) {
  const float* x      = (const float*)d_in[0];
  const int*   ei     = (const int*)d_in[1];
  const int*   batch  = (const int*)d_in[2];
  const float* gat_w  = (const float*)d_in[3];
  const float* asrc   = (const float*)d_in[4];
  const float* adst   = (const float*)d_in[5];
  const float* gat_b  = (const float*)d_in[6];
  const float* gin_w1 = (const float*)d_in[7];
  const float* gin_b1 = (const float*)d_in[8];
  const float* gin_w2 = (const float*)d_in[9];
  const float* gin_b2 = (const float*)d_in[10];
  const float* ec_w1  = (const float*)d_in[11];
  const float* ec_b1  = (const float*)d_in[12];
  const float* ec_w2  = (const float*)d_in[13];
  const float* ec_b2  = (const float*)d_in[14];
  const float* fg1_w = (const float*)d_in[15]; const float* fg1_b = (const float*)d_in[16];
  const float* fg2_w = (const float*)d_in[17]; const float* fg2_b = (const float*)d_in[18];
  const float* fg3_w = (const float*)d_in[19]; const float* fg3_b = (const float*)d_in[20];
  const float* fg4_w = (const float*)d_in[21]; const float* fg4_b = (const float*)d_in[22];
  const float* fg5_w = (const float*)d_in[23]; const float* fg5_b = (const float*)d_in[24];
  const float* fg6_w = (const float*)d_in[25]; const float* fg6_b = (const float*)d_in[26];
  const float* fc1_w = (const float*)d_in[27]; const float* fc1_b = (const float*)d_in[28];
  const float* fc2_w = (const float*)d_in[29]; const float* fc2_b = (const float*)d_in[30];
  const float* out_w = (const float*)d_in[31]; const float* out_b = (const float*)d_in[32];
  float* out = (float*)d_out;

  char* ws = (char*)d_ws;
  size_t off = 0;
  auto alloc = [&](size_t bytes) -> void* {
    void* p = ws + off;
    off = (off + bytes + 255) & ~(size_t)255;
    return p;
  };
  // --- zero region (one memset): rp | cnt | pooled ---
  size_t zoff0 = off;
  int*   rp     = (int*)alloc((N_NODES + 1) * sizeof(int));
  int*   cnt    = (int*)alloc(BATCH * sizeof(int));
  float* pooled = (float*)alloc((size_t)BATCH * POOLW * sizeof(float));
  size_t zbytes = off - zoff0;
  // --- rest ---
  int*   cursor = (int*)alloc(N_NODES * sizeof(int));
  int*   bsum   = (int*)alloc(256 * sizeof(int));
  int*   colidx = (int*)alloc(N_EDGES * sizeof(int));
  float* xh     = (float*)alloc((size_t)N_NODES * HF * sizeof(float));
  float* alS    = (float*)alloc((size_t)N_NODES * 4 * sizeof(float));
  float* alD    = (float*)alloc((size_t)N_NODES * 4 * sizeof(float));
  float* Ubuf   = (float*)alloc((size_t)N_NODES * F2 * sizeof(float));
  float* Vbuf   = (float*)alloc((size_t)N_NODES * F2 * sizeof(float));
  float* cAl    = (float*)alloc(FDIM * 8 * sizeof(float));
  float* Wp     = (float*)alloc((size_t)FDIM * NPACK * sizeof(float));
  float* bpk    = (float*)alloc(NPACK * sizeof(float));
  float* t1     = (float*)alloc((size_t)BATCH * 256 * sizeof(float));
  float* cat    = (float*)alloc((size_t)BATCH * 384 * sizeof(float));
  float* t3     = (float*)alloc((size_t)BATCH * 128 * sizeof(float));
  float* t4     = (float*)alloc((size_t)BATCH * 64 * sizeof(float));
  (void)ws_size; (void)in_sizes; (void)n_in; (void)out_size;

  hipMemsetAsync(ws + zoff0, 0, zbytes, stream);

  k_cal<<<1, 448, 0, stream>>>(gat_w, asrc, adst, cAl);
  k_prep<<<(FDIM * NPACK + 255) / 256, 256, 0, stream>>>(gat_w, ec_w1, ec_b1, cAl, Wp, bpk);
  k_gemm<<<((N_NODES + GM - 1) / GM) * 3, 256, 0, stream>>>(x, Wp, bpk,
                                                            xh, Ubuf, Vbuf, alS, alD);
  k_hist<<<(N_EDGES + 255) / 256, 256, 0, stream>>>(ei, batch, rp, cnt);
  k_scan1<<<SCAN_BLOCKS, 256, 0, stream>>>(rp, bsum);
  k_scan2<<<1, 256, 0, stream>>>(bsum);
  k_scan3<<<SCAN_BLOCKS, 256, 0, stream>>>(bsum, rp, cursor);
  k_scatter<<<(N_EDGES + 255) / 256, 256, 0, stream>>>(ei, cursor, colidx);

  k_gat<<<(N_NODES + 3) / 4, 256, 0, stream>>>(xh, alS, alD, gat_b, rp, colidx, batch, pooled);
  k_gin<<<(N_NODES + 3) / 4, 256, 0, stream>>>(x, gin_w1, gin_b1, gin_w2, gin_b2,
                                               rp, colidx, batch, pooled);
  k_ec<<<2048, 256, 0, stream>>>(Ubuf, Vbuf, ec_w2, ec_b2, rp, colidx, batch, pooled);

  k_pooldiv<<<(BATCH * POOLW + 255) / 256, 256, 0, stream>>>(pooled, cnt);

  // heads: gat | gin | ec -> cat[128,384]
  k_dense<<<(128 * 256 + 255) / 256, 256, 0, stream>>>(pooled + 0, POOLW, fg1_w, fg1_b, t1, 256, 128, HF, 256, 1);
  k_dense<<<(128 * 128 + 255) / 256, 256, 0, stream>>>(t1, 256, fg2_w, fg2_b, cat + 0, 384, 128, 256, 128, 1);
  k_dense<<<(128 * 256 + 255) / 256, 256, 0, stream>>>(pooled + HF, POOLW, fg3_w, fg3_b, t1, 256, 128, F2, 256, 1);
  k_dense<<<(128 * 128 + 255) / 256, 256, 0, stream>>>(t1, 256, fg4_w, fg4_b, cat + 128, 384, 128, 256, 128, 1);
  k_dense<<<(128 * 256 + 255) / 256, 256, 0, stream>>>(pooled + HF + F2, POOLW, fg5_w, fg5_b, t1, 256, 128, F2, 256, 1);
  k_dense<<<(128 * 128 + 255) / 256, 256, 0, stream>>>(t1, 256, fg6_w, fg6_b, cat + 256, 384, 128, 256, 128, 1);
  // final MLP
  k_dense<<<(128 * 128 + 255) / 256, 256, 0, stream>>>(cat, 384, fc1_w, fc1_b, t3, 128, 128, 384, 128, 1);
  k_dense<<<(128 * 64 + 255) / 256, 256, 0, stream>>>(t3, 128, fc2_w, fc2_b, t4, 64, 128, 128, 64, 1);
  k_dense<<<1, 128, 0, stream>>>(t4, 64, out_w, out_b, out, 1, 128, 64, 1, 2);
}